// Round 4
// baseline (265.413 us; speedup 1.0000x reference)
//
#include <hip/hip_runtime.h>
#include <hip/hip_bf16.h>
#include <math.h>

typedef __bf16 bf16x8v __attribute__((ext_vector_type(8)));
typedef __bf16 bf16x4v __attribute__((ext_vector_type(4)));
typedef float  f32x4   __attribute__((ext_vector_type(4)));

#define D_DIM 512
#define P_DIM 128
#define LDB   520            // bf16 per LDS B row: 512 + 8 pad -> 260 dwords stride.
                             // 260 % 32 == 4 -> ds_read_b128 conflict-free.
#define TEMP  0.1f
#define ROWS_PER_BLOCK 256
#define THREADS 1024

// 256 blocks (1/CU, LDS-limited) x 16 waves. B (prototypes) persistent in LDS.
// Each wave owns 16 rows x all 128 prototypes; NO barriers in the main loop.
// R4: no NT hints (L2 path), prefetch distance 4, fully unrolled K loop.
__global__ __launch_bounds__(THREADS, 4)
void mrc_fused(const float* __restrict__ bfeat,
               const float* __restrict__ protos,
               const int*   __restrict__ labels,
               const float* __restrict__ weights,
               float*       __restrict__ out,
               int nrows)
{
    __shared__ __bf16 sB[P_DIM * LDB];   // 133120 B
    __shared__ float  sRed[16];

    const int t    = threadIdx.x;
    const int lane = t & 63;
    const int wave = t >> 6;
    const int q    = lane >> 4;   // quad 0..3
    const int cl   = lane & 15;

    const long long r0 = (long long)blockIdx.x * ROWS_PER_BLOCK + wave * 16;

    // ---- label prefetch: issue the 32 scattered dword loads NOW so they
    // complete under the GEMM stream; consumed from registers in the epilogue.
    // lane(cl,q) needs labels[row = q*4+reg][col = ct*16+cl]
    int lab[4][8];
    {
        const int* lbase = labels + r0 * (long long)P_DIM;
#pragma unroll
        for (int reg = 0; reg < 4; ++reg)
#pragma unroll
            for (int ct = 0; ct < 8; ++ct)
                lab[reg][ct] = lbase[(q * 4 + reg) * P_DIM + ct * 16 + cl];
    }

    // ---- stage prototypes fp32 -> bf16 into LDS, once per block ----
#pragma unroll
    for (int i = 0; i < 16; ++i) {
        const int f   = i * THREADS + t;     // 0..16383 float4s
        const int row = f >> 7;              // /128
        const int c4  = f & 127;
        const f32x4 v = *(const f32x4*)(protos + row * D_DIM + c4 * 4);
        bf16x4v b;
        b[0] = (__bf16)v[0]; b[1] = (__bf16)v[1]; b[2] = (__bf16)v[2]; b[3] = (__bf16)v[3];
        *(bf16x4v*)&sB[row * LDB + c4 * 4] = b;
    }
    __syncthreads();   // the only block-wide barrier before the final reduction

    // ---- each wave: 16 rows, direct global->register A fragments ----
    // A-operand layout for mfma_f32_16x16x32_bf16: A[m = lane&15][k = q*8 + j]
    const float* arow = bfeat + (r0 + cl) * (long long)D_DIM + q * 8;

    float wcol[8];
#pragma unroll
    for (int ct = 0; ct < 8; ++ct) wcol[ct] = weights[ct * 16 + cl];

    f32x4 acc[8];
#pragma unroll
    for (int ct = 0; ct < 8; ++ct) acc[ct] = (f32x4){0.f, 0.f, 0.f, 0.f};

    float ss = 0.f;
    // distance-4 prefetch: 8 float4 (8 KB/wave) in flight
    f32x4 p[4][2];
#pragma unroll
    for (int i = 0; i < 4; ++i) {
        p[i][0] = *(const f32x4*)(arow + i * 32);
        p[i][1] = *(const f32x4*)(arow + i * 32 + 4);
    }

#pragma unroll
    for (int ks = 0; ks < 16; ++ks) {
        const f32x4 c0 = p[ks & 3][0], c1 = p[ks & 3][1];
        if (ks < 12) {   // static guard (fully unrolled)
            p[ks & 3][0] = *(const f32x4*)(arow + (ks + 4) * 32);
            p[ks & 3][1] = *(const f32x4*)(arow + (ks + 4) * 32 + 4);
        }
        ss += c0[0]*c0[0] + c0[1]*c0[1] + c0[2]*c0[2] + c0[3]*c0[3]
            + c1[0]*c1[0] + c1[1]*c1[1] + c1[2]*c1[2] + c1[3]*c1[3];
        bf16x8v af;
        af[0]=(__bf16)c0[0]; af[1]=(__bf16)c0[1]; af[2]=(__bf16)c0[2]; af[3]=(__bf16)c0[3];
        af[4]=(__bf16)c1[0]; af[5]=(__bf16)c1[1]; af[6]=(__bf16)c1[2]; af[7]=(__bf16)c1[3];
        const int k0 = ks * 32 + q * 8;
#pragma unroll
        for (int ct = 0; ct < 8; ++ct) {
            const bf16x8v bfr = *(const bf16x8v*)&sB[(ct * 16 + cl) * LDB + k0];
            acc[ct] = __builtin_amdgcn_mfma_f32_16x16x32_bf16(af, bfr, acc[ct], 0, 0, 0);
        }
    }

    // ---- row norms: lane(cl,q) holds 128 of row cl's 512 squares ----
    ss += __shfl_xor(ss, 16);
    ss += __shfl_xor(ss, 32);
    const float scale = 1.0f / (fmaxf(sqrtf(ss), 1e-12f) * TEMP);  // for row cl

    // ---- epilogue: masked log-softmax per row ----
    // C/D layout: col = ct*16 + (lane&15), row = q*4 + reg
    float pos_acc = 0.f;
#pragma unroll
    for (int reg = 0; reg < 4; ++reg) {
        const float rscale = __shfl(scale, q * 4 + reg, 16);  // scale lives in lane cl==row
        float lg[8];
        float m = -3.4e38f;
#pragma unroll
        for (int ct = 0; ct < 8; ++ct) {
            lg[ct] = acc[ct][reg] * rscale;
            m = fmaxf(m, lg[ct]);
        }
        m = fmaxf(m, __shfl_xor(m, 1, 16));
        m = fmaxf(m, __shfl_xor(m, 2, 16));
        m = fmaxf(m, __shfl_xor(m, 4, 16));
        m = fmaxf(m, __shfl_xor(m, 8, 16));

        float s = 0.f, pz = 0.f, msum = 0.f;
#pragma unroll
        for (int ct = 0; ct < 8; ++ct) {
            const float mask = (float)lab[reg][ct] * wcol[ct];
            const float z = lg[ct] - m;
            s    += __expf(z) * (1.0f - mask);
            pz   += mask * z;
            msum += mask;
        }
        s += __shfl_xor(s, 1, 16);
        s += __shfl_xor(s, 2, 16);
        s += __shfl_xor(s, 4, 16);
        s += __shfl_xor(s, 8, 16);
        // sum(mask*(z - log S)) = sum(mask*z) - log(S)*sum(mask)
        pos_acc += pz - logf(s) * msum;
    }

    // ---- block reduction -> one atomicAdd ----
    pos_acc += __shfl_xor(pos_acc, 1);
    pos_acc += __shfl_xor(pos_acc, 2);
    pos_acc += __shfl_xor(pos_acc, 4);
    pos_acc += __shfl_xor(pos_acc, 8);
    pos_acc += __shfl_xor(pos_acc, 16);
    pos_acc += __shfl_xor(pos_acc, 32);
    if (lane == 0) sRed[wave] = pos_acc;
    __syncthreads();
    if (t == 0) {
        float total = 0.f;
#pragma unroll
        for (int w = 0; w < 16; ++w) total += sRed[w];
        // loss = LAMBDA * (-(T/BT) * sum(mean_log_prob_pos)) / n ; LAMBDA=1, BT=1
        atomicAdd(out, total * (-TEMP / (float)nrows));
    }
}

extern "C" void kernel_launch(void* const* d_in, const int* in_sizes, int n_in,
                              void* d_out, int out_size, void* d_ws, size_t ws_size,
                              hipStream_t stream) {
    const float* bfeat   = (const float*)d_in[2];
    const float* protos  = (const float*)d_in[3];
    const int*   labels  = (const int*)d_in[4];
    const float* weights = (const float*)d_in[5];
    float* out = (float*)d_out;

    const int nrows = in_sizes[2] / D_DIM;         // 65536

    hipMemsetAsync(d_out, 0, sizeof(float) * out_size, stream);
    const int nblocks = nrows / ROWS_PER_BLOCK;    // 256
    mrc_fused<<<nblocks, THREADS, 0, stream>>>(bfeat, protos, labels, weights, out, nrows);
}

// Round 5
// 259.285 us; speedup vs baseline: 1.0236x; 1.0236x over previous
//
#include <hip/hip_runtime.h>
#include <hip/hip_bf16.h>
#include <math.h>

typedef __bf16 bf16x8v __attribute__((ext_vector_type(8)));
typedef float  f32x4   __attribute__((ext_vector_type(4)));

#define D_DIM 512
#define P_DIM 128
#define TEMP  0.1f
#define ROWS_PER_BLOCK 256
#define THREADS 1024

// 256 blocks (1/CU, LDS-limited) x 16 waves. B (prototypes) persistent in LDS
// in FRAGMENT ORDER: sB[((ct*16+... o = ct*1024 + ks*64 + q*16 + cl) * 8 bf16.
// A wave's ds_read_b128 is lane-contiguous -> conflict-free; staging writes
// are lane-contiguous bf16x8 -> conflict-free. No barriers in the main loop.
// R5: __launch_bounds__(1024) only (VGPR cap 128, was 64 -> spills), labels
// packed to 1 bit each (saves 31 VGPRs), prefetch distance 4 kept.
__global__ __launch_bounds__(THREADS)
void mrc_fused(const float* __restrict__ bfeat,
               const float* __restrict__ protos,
               const int*   __restrict__ labels,
               const float* __restrict__ weights,
               float*       __restrict__ out,
               int nrows)
{
    __shared__ __bf16 sB[P_DIM * D_DIM];   // 131072 B, fragment-ordered
    __shared__ float  sRed[16];

    const int t    = threadIdx.x;
    const int lane = t & 63;
    const int wave = t >> 6;
    const int q    = lane >> 4;   // quad 0..3
    const int cl   = lane & 15;

    const long long r0 = (long long)blockIdx.x * ROWS_PER_BLOCK + wave * 16;

    // ---- labels: issue 32 scattered dword loads now, pack to 32 bits.
    // lane(cl,q) needs labels[row = q*4+reg][col = ct*16+cl], bit = reg*8+ct.
    unsigned int labbits = 0;
    {
        const int* lbase = labels + r0 * (long long)P_DIM + q * 4 * P_DIM + cl;
#pragma unroll
        for (int reg = 0; reg < 4; ++reg)
#pragma unroll
            for (int ct = 0; ct < 8; ++ct)
                labbits |= (unsigned)(lbase[reg * P_DIM + ct * 16] & 1) << (reg * 8 + ct);
    }

    // ---- stage prototypes fp32 -> bf16 into LDS, fragment order ----
    // octet index o: cl=o&15, q=(o>>4)&3, ks=(o>>6)&15, ct=o>>10
#pragma unroll
    for (int i = 0; i < 8; ++i) {
        const int o   = i * THREADS + t;           // 0..8191
        const int p   = ((o >> 10) << 4) | (o & 15);          // proto row
        const int k   = (((o >> 6) & 15) << 5) | (((o >> 4) & 3) << 3);
        const f32x4 v0 = *(const f32x4*)(protos + p * D_DIM + k);
        const f32x4 v1 = *(const f32x4*)(protos + p * D_DIM + k + 4);
        bf16x8v b;
        b[0]=(__bf16)v0[0]; b[1]=(__bf16)v0[1]; b[2]=(__bf16)v0[2]; b[3]=(__bf16)v0[3];
        b[4]=(__bf16)v1[0]; b[5]=(__bf16)v1[1]; b[6]=(__bf16)v1[2]; b[7]=(__bf16)v1[3];
        *(bf16x8v*)&sB[o * 8] = b;                 // lane-contiguous 16 B
    }
    __syncthreads();   // the only block-wide barrier before the final reduction

    // ---- each wave: 16 rows, direct global->register A fragments ----
    // A-operand layout for mfma_f32_16x16x32_bf16: A[m = lane&15][k = q*8 + j]
    const float* arow = bfeat + (r0 + cl) * (long long)D_DIM + q * 8;

    float wcol[8];
#pragma unroll
    for (int ct = 0; ct < 8; ++ct) wcol[ct] = weights[ct * 16 + cl];

    f32x4 acc[8];
#pragma unroll
    for (int ct = 0; ct < 8; ++ct) acc[ct] = (f32x4){0.f, 0.f, 0.f, 0.f};

    float ss = 0.f;
    // distance-4 prefetch: 8 float4 (8 KB/wave) in flight
    f32x4 p[4][2];
#pragma unroll
    for (int i = 0; i < 4; ++i) {
        p[i][0] = *(const f32x4*)(arow + i * 32);
        p[i][1] = *(const f32x4*)(arow + i * 32 + 4);
    }

#pragma unroll
    for (int ks = 0; ks < 16; ++ks) {
        const f32x4 c0 = p[ks & 3][0], c1 = p[ks & 3][1];
        if (ks < 12) {   // static guard (fully unrolled)
            p[ks & 3][0] = *(const f32x4*)(arow + (ks + 4) * 32);
            p[ks & 3][1] = *(const f32x4*)(arow + (ks + 4) * 32 + 4);
        }
        ss += c0[0]*c0[0] + c0[1]*c0[1] + c0[2]*c0[2] + c0[3]*c0[3]
            + c1[0]*c1[0] + c1[1]*c1[1] + c1[2]*c1[2] + c1[3]*c1[3];
        bf16x8v af;
        af[0]=(__bf16)c0[0]; af[1]=(__bf16)c0[1]; af[2]=(__bf16)c0[2]; af[3]=(__bf16)c0[3];
        af[4]=(__bf16)c1[0]; af[5]=(__bf16)c1[1]; af[6]=(__bf16)c1[2]; af[7]=(__bf16)c1[3];
        const int base = (ks << 6) + (q << 4) + cl;   // + ct<<10, all *8
#pragma unroll
        for (int ct = 0; ct < 8; ++ct) {
            const bf16x8v bfr = *(const bf16x8v*)&sB[(base + (ct << 10)) * 8];
            acc[ct] = __builtin_amdgcn_mfma_f32_16x16x32_bf16(af, bfr, acc[ct], 0, 0, 0);
        }
    }

    // ---- row norms: lane(cl,q) holds 128 of row cl's 512 squares ----
    ss += __shfl_xor(ss, 16);
    ss += __shfl_xor(ss, 32);
    const float scale = 1.0f / (fmaxf(sqrtf(ss), 1e-12f) * TEMP);  // for row cl

    // ---- epilogue: masked log-softmax per row ----
    // C/D layout: col = ct*16 + (lane&15), row = q*4 + reg
    float pos_acc = 0.f;
#pragma unroll
    for (int reg = 0; reg < 4; ++reg) {
        const float rscale = __shfl(scale, q * 4 + reg, 16);  // scale lives in lane cl==row
        float lg[8];
        float m = -3.4e38f;
#pragma unroll
        for (int ct = 0; ct < 8; ++ct) {
            lg[ct] = acc[ct][reg] * rscale;
            m = fmaxf(m, lg[ct]);
        }
        m = fmaxf(m, __shfl_xor(m, 1, 16));
        m = fmaxf(m, __shfl_xor(m, 2, 16));
        m = fmaxf(m, __shfl_xor(m, 4, 16));
        m = fmaxf(m, __shfl_xor(m, 8, 16));

        float s = 0.f, pz = 0.f, msum = 0.f;
#pragma unroll
        for (int ct = 0; ct < 8; ++ct) {
            const float mask = ((labbits >> (reg * 8 + ct)) & 1u) ? wcol[ct] : 0.f;
            const float z = lg[ct] - m;
            s    += __expf(z) * (1.0f - mask);
            pz   += mask * z;
            msum += mask;
        }
        s += __shfl_xor(s, 1, 16);
        s += __shfl_xor(s, 2, 16);
        s += __shfl_xor(s, 4, 16);
        s += __shfl_xor(s, 8, 16);
        // sum(mask*(z - log S)) = sum(mask*z) - log(S)*sum(mask)
        pos_acc += pz - logf(s) * msum;
    }

    // ---- block reduction -> one atomicAdd ----
    pos_acc += __shfl_xor(pos_acc, 1);
    pos_acc += __shfl_xor(pos_acc, 2);
    pos_acc += __shfl_xor(pos_acc, 4);
    pos_acc += __shfl_xor(pos_acc, 8);
    pos_acc += __shfl_xor(pos_acc, 16);
    pos_acc += __shfl_xor(pos_acc, 32);
    if (lane == 0) sRed[wave] = pos_acc;
    __syncthreads();
    if (t == 0) {
        float total = 0.f;
#pragma unroll
        for (int w = 0; w < 16; ++w) total += sRed[w];
        // loss = LAMBDA * (-(T/BT) * sum(mean_log_prob_pos)) / n ; LAMBDA=1, BT=1
        atomicAdd(out, total * (-TEMP / (float)nrows));
    }
}

extern "C" void kernel_launch(void* const* d_in, const int* in_sizes, int n_in,
                              void* d_out, int out_size, void* d_ws, size_t ws_size,
                              hipStream_t stream) {
    const float* bfeat   = (const float*)d_in[2];
    const float* protos  = (const float*)d_in[3];
    const int*   labels  = (const int*)d_in[4];
    const float* weights = (const float*)d_in[5];
    float* out = (float*)d_out;

    const int nrows = in_sizes[2] / D_DIM;         // 65536

    hipMemsetAsync(d_out, 0, sizeof(float) * out_size, stream);
    const int nblocks = nrows / ROWS_PER_BLOCK;    // 256
    mrc_fused<<<nblocks, THREADS, 0, stream>>>(bfeat, protos, labels, weights, out, nrows);
}